// Round 12
// baseline (421.095 us; speedup 1.0000x reference)
//
#include <hip/hip_runtime.h>
#include <hip/hip_cooperative_groups.h>
#include <math.h>

namespace cg = cooperative_groups;

#define N_NODES 10000
#define N_EDGES 320000
#define ET (N_EDGES + N_NODES)        // edges + self-loops
#define CAP 128                       // per-node CSR bucket capacity (max deg ~60)
#define NB_G1 (157 * 5)               // gemm1 virtual blocks
#define NB_SCT ((ET + 255) / 256)     // scatter virtual blocks
#define NB_PH1 (NB_G1 + NB_SCT)
#define NB_AGG1 (2500 * 5)
#define NB_G2 (157 * 5)
#define NB_HRED 2500
#define NB_AGG2 2500

__device__ __forceinline__ float lrelu_exp(float e) {
  e = (e > 0.f) ? e : 0.2f * e;   // leaky_relu
  return __expf(e);               // logits O(+-6): no max-shift needed
}

__global__ __launch_bounds__(256) void k_mega(
    const float* __restrict__ x, const float* __restrict__ W1,
    const float* __restrict__ as1w, const float* __restrict__ ad1w, const float* __restrict__ b1,
    const float* __restrict__ W2, const float* __restrict__ as2w, const float* __restrict__ ad2w,
    const float* __restrict__ b2, const int* __restrict__ ei,
    int* __restrict__ cursor, int* __restrict__ csr,
    float* __restrict__ h1, float* __restrict__ out1, float* __restrict__ h2part,
    float* __restrict__ h2, float* __restrict__ a_src1, float* __restrict__ a_dst1,
    float* __restrict__ a_src2, float* __restrict__ a_dst2, float* __restrict__ out) {
  cg::grid_group grid = cg::this_grid();
  __shared__ float xs[128][65];
  int t = threadIdx.x;
  int lane = t & 63, wid = t >> 6;
  int nb = gridDim.x;

  // ---- phase 0: zero cursor ----
  for (int i = blockIdx.x * 256 + t; i < N_NODES; i += nb * 256) cursor[i] = 0;
  grid.sync();

  // ---- phase 1: gemm1 (vb 0..784) + bucket scatter (rest) ----
  for (int vb = blockIdx.x; vb < NB_PH1; vb += nb) {
    if (vb >= NB_G1) {
      int i = (vb - NB_G1) * 256 + t;
      if (i < ET) {
        int src, dst;
        if (i < N_EDGES) { src = ei[i]; dst = ei[N_EDGES + i]; }
        else             { src = dst = i - N_EDGES; }
        int pos = (dst << 7) + atomicAdd(&cursor[dst], 1);
        csr[pos] = src;
      }
    } else {
      int h = vb / 157;
      int rb = (vb % 157) * 64;
#pragma unroll
      for (int i = 0; i < 8; ++i) {
        int idx = t + 256 * i;
        int kq = (idx & 31) * 4;
        int row = idx >> 5;
        int gr = rb + row;
        float4 v = make_float4(0.f, 0.f, 0.f, 0.f);
        if (gr < N_NODES) v = *reinterpret_cast<const float4*>(&x[(size_t)gr * 128 + kq]);
        xs[kq + 0][row] = v.x; xs[kq + 1][row] = v.y; xs[kq + 2][row] = v.z; xs[kq + 3][row] = v.w;
      }
      __syncthreads();
      int cg_ = t & 15, rg = t >> 4;
      int c0 = cg_ * 4, r0 = rg * 4;
      const float* __restrict__ wp = W1 + h * 64 + c0;
      float4 a0 = make_float4(0.f,0.f,0.f,0.f), a1 = a0, a2 = a0, a3 = a0;
#pragma unroll 4
      for (int k = 0; k < 128; ++k) {
        float4 xv = *reinterpret_cast<const float4*>(&xs[k][r0]);
        float4 wv = *reinterpret_cast<const float4*>(&wp[(size_t)k * 320]);
        a0.x = fmaf(xv.x, wv.x, a0.x); a0.y = fmaf(xv.x, wv.y, a0.y); a0.z = fmaf(xv.x, wv.z, a0.z); a0.w = fmaf(xv.x, wv.w, a0.w);
        a1.x = fmaf(xv.y, wv.x, a1.x); a1.y = fmaf(xv.y, wv.y, a1.y); a1.z = fmaf(xv.y, wv.z, a1.z); a1.w = fmaf(xv.y, wv.w, a1.w);
        a2.x = fmaf(xv.z, wv.x, a2.x); a2.y = fmaf(xv.z, wv.y, a2.y); a2.z = fmaf(xv.z, wv.z, a2.z); a2.w = fmaf(xv.z, wv.w, a2.w);
        a3.x = fmaf(xv.w, wv.x, a3.x); a3.y = fmaf(xv.w, wv.y, a3.y); a3.z = fmaf(xv.w, wv.z, a3.z); a3.w = fmaf(xv.w, wv.w, a3.w);
      }
      float4 asv = *reinterpret_cast<const float4*>(&as1w[h * 64 + c0]);
      float4 adv = *reinterpret_cast<const float4*>(&ad1w[h * 64 + c0]);
#pragma unroll
      for (int rr = 0; rr < 4; ++rr) {
        float4 ar = (rr == 0) ? a0 : (rr == 1) ? a1 : (rr == 2) ? a2 : a3;
        float vs = ar.x * asv.x + ar.y * asv.y + ar.z * asv.z + ar.w * asv.w;
        float vd = ar.x * adv.x + ar.y * adv.y + ar.z * adv.z + ar.w * adv.w;
#pragma unroll
        for (int m = 1; m < 16; m <<= 1) { vs += __shfl_xor(vs, m); vd += __shfl_xor(vd, m); }
        int gr = rb + r0 + rr;
        if (gr < N_NODES) {
          if (cg_ == 0) { a_src1[h * N_NODES + gr] = vs; a_dst1[h * N_NODES + gr] = vd; }
          *reinterpret_cast<float4*>(&h1[(size_t)gr * 320 + h * 64 + c0]) = ar;
        }
      }
      __syncthreads();                      // protect xs before next vb restage
    }
  }
  grid.sync();

  // ---- phase 2: agg1 (12500 vb = 2500 node-groups x 5 heads) ----
  for (int vb = blockIdx.x; vb < NB_AGG1; vb += nb) {
    int h = vb / 2500;
    int n = (vb - h * 2500) * 4 + wid;
    int sub = lane >> 4;
    int cq = lane & 15;
    int beg = n << 7;
    int deg = cursor[n];
    int limit = beg + deg;
    int end = beg + ((deg + 15) & ~15);
    const float* __restrict__ as = a_src1 + (size_t)h * N_NODES;
    float adn = a_dst1[(size_t)h * N_NODES + n];
    const float* __restrict__ hh = h1 + h * 64 + cq * 4;
    float4 acc = make_float4(0.f, 0.f, 0.f, 0.f);
    float s = 0.f;
    int e = beg + sub;
    bool va = e < limit, vb_ = e + 4 < limit, vc = e + 8 < limit, vd = e + 12 < limit;
    int t0 = csr[e], t1 = csr[e + 4], t2 = csr[e + 8], t3 = csr[e + 12];
    unsigned i0 = va ? (unsigned)t0 : 0u, i1 = vb_ ? (unsigned)t1 : 0u;
    unsigned i2 = vc ? (unsigned)t2 : 0u, i3 = vd ? (unsigned)t3 : 0u;
    float v0 = as[i0], v1 = as[i1], v2 = as[i2], v3 = as[i3];
    for (;;) {
      float4 ga = *reinterpret_cast<const float4*>(hh + i0 * 320u);
      float4 gb = *reinterpret_cast<const float4*>(hh + i1 * 320u);
      float4 gc = *reinterpret_cast<const float4*>(hh + i2 * 320u);
      float4 gd = *reinterpret_cast<const float4*>(hh + i3 * 320u);
      float pa = va ? lrelu_exp(v0 + adn) : 0.f;
      float pb = vb_ ? lrelu_exp(v1 + adn) : 0.f;
      float pc = vc ? lrelu_exp(v2 + adn) : 0.f;
      float pd = vd ? lrelu_exp(v3 + adn) : 0.f;
      e += 16;
      bool more = e < end;
      if (more) {
        va = e < limit; vb_ = e + 4 < limit; vc = e + 8 < limit; vd = e + 12 < limit;
        t0 = csr[e]; t1 = csr[e + 4]; t2 = csr[e + 8]; t3 = csr[e + 12];
        i0 = va ? (unsigned)t0 : 0u; i1 = vb_ ? (unsigned)t1 : 0u;
        i2 = vc ? (unsigned)t2 : 0u; i3 = vd ? (unsigned)t3 : 0u;
        v0 = as[i0]; v1 = as[i1]; v2 = as[i2]; v3 = as[i3];
      }
      s += (pa + pb) + (pc + pd);
      acc.x = fmaf(pd, gd.x, fmaf(pc, gc.x, fmaf(pb, gb.x, fmaf(pa, ga.x, acc.x))));
      acc.y = fmaf(pd, gd.y, fmaf(pc, gc.y, fmaf(pb, gb.y, fmaf(pa, ga.y, acc.y))));
      acc.z = fmaf(pd, gd.z, fmaf(pc, gc.z, fmaf(pb, gb.z, fmaf(pa, ga.z, acc.z))));
      acc.w = fmaf(pd, gd.w, fmaf(pc, gc.w, fmaf(pb, gb.w, fmaf(pa, ga.w, acc.w))));
      if (!more) break;
    }
#pragma unroll
    for (int m = 16; m <= 32; m <<= 1) {
      acc.x += __shfl_xor(acc.x, m);
      acc.y += __shfl_xor(acc.y, m);
      acc.z += __shfl_xor(acc.z, m);
      acc.w += __shfl_xor(acc.w, m);
      s += __shfl_xor(s, m);
    }
    if (sub == 0) {
      float inv = 1.f / (s + 1e-16f);
      const float* bp = b1 + h * 64 + cq * 4;
      float4 o;
      o.x = fmaxf(fmaf(acc.x, inv, bp[0]), 0.f);
      o.y = fmaxf(fmaf(acc.y, inv, bp[1]), 0.f);
      o.z = fmaxf(fmaf(acc.z, inv, bp[2]), 0.f);
      o.w = fmaxf(fmaf(acc.w, inv, bp[3]), 0.f);
      *reinterpret_cast<float4*>(&out1[(size_t)n * 320 + h * 64 + cq * 4]) = o;
    }
  }
  grid.sync();

  // ---- phase 3: gemm2 split-K (785 vb = 157 row-tiles x 5 K-chunks) ----
  for (int vb = blockIdx.x; vb < NB_G2; vb += nb) {
    int kc = vb / 157;
    int rb = (vb - kc * 157) * 64;
#pragma unroll
    for (int i = 0; i < 4; ++i) {
      int idx = t + 256 * i;
      int kq = (idx & 15) * 4;
      int row = idx >> 4;
      int gr = rb + row;
      float4 v = make_float4(0.f, 0.f, 0.f, 0.f);
      if (gr < N_NODES) v = *reinterpret_cast<const float4*>(&out1[(size_t)gr * 320 + kc * 64 + kq]);
      xs[kq + 0][row] = v.x; xs[kq + 1][row] = v.y; xs[kq + 2][row] = v.z; xs[kq + 3][row] = v.w;
    }
    __syncthreads();
    int cg_ = t & 15, rg = t >> 4;
    int c0 = cg_ * 4, r0 = rg * 4;
    const float* __restrict__ wp = W2 + (size_t)kc * 64 * 64 + c0;
    float4 a0 = make_float4(0.f,0.f,0.f,0.f), a1 = a0, a2 = a0, a3 = a0;
#pragma unroll 4
    for (int k = 0; k < 64; ++k) {
      float4 xv = *reinterpret_cast<const float4*>(&xs[k][r0]);
      float4 wv = *reinterpret_cast<const float4*>(&wp[(size_t)k * 64]);
      a0.x = fmaf(xv.x, wv.x, a0.x); a0.y = fmaf(xv.x, wv.y, a0.y); a0.z = fmaf(xv.x, wv.z, a0.z); a0.w = fmaf(xv.x, wv.w, a0.w);
      a1.x = fmaf(xv.y, wv.x, a1.x); a1.y = fmaf(xv.y, wv.y, a1.y); a1.z = fmaf(xv.y, wv.z, a1.z); a1.w = fmaf(xv.y, wv.w, a1.w);
      a2.x = fmaf(xv.z, wv.x, a2.x); a2.y = fmaf(xv.z, wv.y, a2.y); a2.z = fmaf(xv.z, wv.z, a2.z); a2.w = fmaf(xv.z, wv.w, a2.w);
      a3.x = fmaf(xv.w, wv.x, a3.x); a3.y = fmaf(xv.w, wv.y, a3.y); a3.z = fmaf(xv.w, wv.z, a3.z); a3.w = fmaf(xv.w, wv.w, a3.w);
    }
    float* __restrict__ hp = h2part + (size_t)kc * N_NODES * 64;
#pragma unroll
    for (int rr = 0; rr < 4; ++rr) {
      float4 ar = (rr == 0) ? a0 : (rr == 1) ? a1 : (rr == 2) ? a2 : a3;
      int gr = rb + r0 + rr;
      if (gr < N_NODES) *reinterpret_cast<float4*>(&hp[(size_t)gr * 64 + c0]) = ar;
    }
    __syncthreads();
  }
  grid.sync();

  // ---- phase 4: reduce 5 partials + att dots ----
  for (int vb = blockIdx.x; vb < NB_HRED; vb += nb) {
    int n = vb * 4 + wid;
    int c = lane;
    float v = 0.f;
#pragma unroll
    for (int kc = 0; kc < 5; ++kc) v += h2part[((size_t)kc * N_NODES + n) * 64 + c];
    float vs = v * as2w[c], vd = v * ad2w[c];
    for (int off = 32; off; off >>= 1) {
      vs += __shfl_down(vs, off);
      vd += __shfl_down(vd, off);
    }
    h2[(size_t)n * 64 + c] = v;
    if (c == 0) { a_src2[n] = vs; a_dst2[n] = vd; }
  }
  grid.sync();

  // ---- phase 5: agg2 ----
  for (int vb = blockIdx.x; vb < NB_AGG2; vb += nb) {
    int n = vb * 4 + wid;
    int sub = lane >> 4;
    int cq = lane & 15;
    int beg = n << 7;
    int deg = cursor[n];
    int limit = beg + deg;
    int end = beg + ((deg + 15) & ~15);
    float adn = a_dst2[n];
    const float* __restrict__ hh = h2 + cq * 4;
    float4 acc = make_float4(0.f, 0.f, 0.f, 0.f);
    float s = 0.f;
    int e = beg + sub;
    bool va = e < limit, vb_ = e + 4 < limit, vc = e + 8 < limit, vd = e + 12 < limit;
    int t0 = csr[e], t1 = csr[e + 4], t2 = csr[e + 8], t3 = csr[e + 12];
    unsigned i0 = va ? (unsigned)t0 : 0u, i1 = vb_ ? (unsigned)t1 : 0u;
    unsigned i2 = vc ? (unsigned)t2 : 0u, i3 = vd ? (unsigned)t3 : 0u;
    float v0 = a_src2[i0], v1 = a_src2[i1], v2 = a_src2[i2], v3 = a_src2[i3];
    for (;;) {
      float4 ga = *reinterpret_cast<const float4*>(hh + i0 * 64u);
      float4 gb = *reinterpret_cast<const float4*>(hh + i1 * 64u);
      float4 gc = *reinterpret_cast<const float4*>(hh + i2 * 64u);
      float4 gd = *reinterpret_cast<const float4*>(hh + i3 * 64u);
      float pa = va ? lrelu_exp(v0 + adn) : 0.f;
      float pb = vb_ ? lrelu_exp(v1 + adn) : 0.f;
      float pc = vc ? lrelu_exp(v2 + adn) : 0.f;
      float pd = vd ? lrelu_exp(v3 + adn) : 0.f;
      e += 16;
      bool more = e < end;
      if (more) {
        va = e < limit; vb_ = e + 4 < limit; vc = e + 8 < limit; vd = e + 12 < limit;
        t0 = csr[e]; t1 = csr[e + 4]; t2 = csr[e + 8]; t3 = csr[e + 12];
        i0 = va ? (unsigned)t0 : 0u; i1 = vb_ ? (unsigned)t1 : 0u;
        i2 = vc ? (unsigned)t2 : 0u; i3 = vd ? (unsigned)t3 : 0u;
        v0 = a_src2[i0]; v1 = a_src2[i1]; v2 = a_src2[i2]; v3 = a_src2[i3];
      }
      s += (pa + pb) + (pc + pd);
      acc.x = fmaf(pd, gd.x, fmaf(pc, gc.x, fmaf(pb, gb.x, fmaf(pa, ga.x, acc.x))));
      acc.y = fmaf(pd, gd.y, fmaf(pc, gc.y, fmaf(pb, gb.y, fmaf(pa, ga.y, acc.y))));
      acc.z = fmaf(pd, gd.z, fmaf(pc, gc.z, fmaf(pb, gb.z, fmaf(pa, ga.z, acc.z))));
      acc.w = fmaf(pd, gd.w, fmaf(pc, gc.w, fmaf(pb, gb.w, fmaf(pa, ga.w, acc.w))));
      if (!more) break;
    }
#pragma unroll
    for (int m = 16; m <= 32; m <<= 1) {
      acc.x += __shfl_xor(acc.x, m);
      acc.y += __shfl_xor(acc.y, m);
      acc.z += __shfl_xor(acc.z, m);
      acc.w += __shfl_xor(acc.w, m);
      s += __shfl_xor(s, m);
    }
    if (sub == 0) {
      float inv = 1.f / (s + 1e-16f);
      const float* bp = b2 + cq * 4;
      float4 o;
      o.x = fmaxf(fmaf(acc.x, inv, bp[0]), 0.f);
      o.y = fmaxf(fmaf(acc.y, inv, bp[1]), 0.f);
      o.z = fmaxf(fmaf(acc.z, inv, bp[2]), 0.f);
      o.w = fmaxf(fmaf(acc.w, inv, bp[3]), 0.f);
      *reinterpret_cast<float4*>(&out[(size_t)n * 64 + cq * 4]) = o;
    }
  }
}

// ---------------- launch ----------------

extern "C" void kernel_launch(void* const* d_in, const int* in_sizes, int n_in,
                              void* d_out, int out_size, void* d_ws, size_t ws_size,
                              hipStream_t stream) {
  (void)in_sizes; (void)n_in; (void)out_size; (void)ws_size;
  const float* x    = (const float*)d_in[0];
  const int*   ei   = (const int*)d_in[1];
  const float* W1   = (const float*)d_in[2];
  const float* as1w = (const float*)d_in[3];
  const float* ad1w = (const float*)d_in[4];
  const float* b1   = (const float*)d_in[5];
  const float* W2   = (const float*)d_in[6];
  const float* as2w = (const float*)d_in[7];
  const float* ad2w = (const float*)d_in[8];
  const float* b2   = (const float*)d_in[9];
  float* out = (float*)d_out;

  char* ws = (char*)d_ws;
  size_t off = 0;
  auto alloc = [&](size_t bytes) -> void* {
    void* p = ws + off;
    off += (bytes + 255) & ~(size_t)255;
    return p;
  };
  float*  h1     = (float*)alloc((size_t)N_NODES * 320 * 4);
  float*  out1   = (float*)alloc((size_t)N_NODES * 320 * 4);
  float*  h2     = (float*)alloc((size_t)N_NODES * 64 * 4);
  float*  h2part = (float*)alloc((size_t)5 * N_NODES * 64 * 4);
  float*  a_src1 = (float*)alloc((size_t)5 * N_NODES * 4);
  float*  a_dst1 = (float*)alloc((size_t)5 * N_NODES * 4);
  float*  a_src2 = (float*)alloc((size_t)N_NODES * 4);
  float*  a_dst2 = (float*)alloc((size_t)N_NODES * 4);
  int*    cursor = (int*)alloc((size_t)N_NODES * 4);
  int*    csr    = (int*)alloc((size_t)N_NODES * CAP * 4);

  int maxBlocksPerCU = 0;
  hipOccupancyMaxActiveBlocksPerMultiprocessor(&maxBlocksPerCU, k_mega, 256, 0);
  if (maxBlocksPerCU < 1) maxBlocksPerCU = 1;
  hipDeviceProp_t prop;
  int dev = 0;
  hipGetDevice(&dev);
  hipGetDeviceProperties(&prop, dev);
  int grid = prop.multiProcessorCount * maxBlocksPerCU;
  if (grid > NB_AGG1) grid = NB_AGG1;

  void* args[] = {
    (void*)&x, (void*)&W1, (void*)&as1w, (void*)&ad1w, (void*)&b1,
    (void*)&W2, (void*)&as2w, (void*)&ad2w, (void*)&b2, (void*)&ei,
    (void*)&cursor, (void*)&csr, (void*)&h1, (void*)&out1, (void*)&h2part,
    (void*)&h2, (void*)&a_src1, (void*)&a_dst1, (void*)&a_src2, (void*)&a_dst2,
    (void*)&out
  };
  hipLaunchCooperativeKernel((const void*)k_mega, dim3(grid), dim3(256), args, 0, stream);
}

// Round 13
// 114.022 us; speedup vs baseline: 3.6931x; 3.6931x over previous
//
#include <hip/hip_runtime.h>
#include <math.h>

#define N_NODES 10000
#define N_EDGES 320000
#define ET (N_EDGES + N_NODES)        // edges + self-loops
#define CAP 128                       // per-node CSR bucket capacity (max deg ~60)
#define NB_G1 (157 * 5)               // gemm1 blocks in fused launch
#define NB_SCT ((ET + 255) / 256)     // scatter blocks in fused launch

__device__ __forceinline__ float lrelu_exp(float e) {
  e = (e > 0.f) ? e : 0.2f * e;   // leaky_relu
  return __expf(e);               // logits O(+-6): no max-shift needed
}

// ---------------- init: zero cursor ----------------

__global__ __launch_bounds__(256) void k_init(int* __restrict__ cursor) {
  int i = blockIdx.x * 256 + threadIdx.x;
  if (i < N_NODES) cursor[i] = 0;
}

// ------- fused: gemm1 (blocks 0..784) + bucket-scatter (rest) -------

__global__ __launch_bounds__(256) void k_gemm1_scatter(const float* __restrict__ x, const float* __restrict__ W1,
                                                       const float* __restrict__ att_src, const float* __restrict__ att_dst,
                                                       float* __restrict__ h1, float* __restrict__ a_src,
                                                       float* __restrict__ a_dst,
                                                       const int* __restrict__ ei, int* __restrict__ cursor,
                                                       int* __restrict__ csr) {
  __shared__ float xs[128][65];
  int bid = blockIdx.x;
  int t = threadIdx.x;
  if (bid >= NB_G1) {                      // ---- scatter path ----
    int i = (bid - NB_G1) * 256 + t;
    if (i < ET) {
      int src, dst;
      if (i < N_EDGES) { src = ei[i]; dst = ei[N_EDGES + i]; }
      else             { src = dst = i - N_EDGES; }
      int pos = (dst << 7) + atomicAdd(&cursor[dst], 1);
      csr[pos] = src;
    }
    return;
  }
  // ---- gemm1 path: 64-row x 64-col tile, head = bid/157 ----
  int h = bid / 157;
  int rb = (bid % 157) * 64;
#pragma unroll
  for (int i = 0; i < 8; ++i) {
    int idx = t + 256 * i;
    int kq = (idx & 31) * 4;
    int row = idx >> 5;
    int gr = rb + row;
    float4 v = make_float4(0.f, 0.f, 0.f, 0.f);
    if (gr < N_NODES) v = *reinterpret_cast<const float4*>(&x[(size_t)gr * 128 + kq]);
    xs[kq + 0][row] = v.x; xs[kq + 1][row] = v.y; xs[kq + 2][row] = v.z; xs[kq + 3][row] = v.w;
  }
  __syncthreads();
  int cg = t & 15, rg = t >> 4;
  int c0 = cg * 4, r0 = rg * 4;
  const float* __restrict__ wp = W1 + h * 64 + c0;
  float4 a0 = make_float4(0.f,0.f,0.f,0.f), a1 = a0, a2 = a0, a3 = a0;
#pragma unroll 4
  for (int k = 0; k < 128; ++k) {
    float4 xv = *reinterpret_cast<const float4*>(&xs[k][r0]);
    float4 wv = *reinterpret_cast<const float4*>(&wp[(size_t)k * 320]);
    a0.x = fmaf(xv.x, wv.x, a0.x); a0.y = fmaf(xv.x, wv.y, a0.y); a0.z = fmaf(xv.x, wv.z, a0.z); a0.w = fmaf(xv.x, wv.w, a0.w);
    a1.x = fmaf(xv.y, wv.x, a1.x); a1.y = fmaf(xv.y, wv.y, a1.y); a1.z = fmaf(xv.y, wv.z, a1.z); a1.w = fmaf(xv.y, wv.w, a1.w);
    a2.x = fmaf(xv.z, wv.x, a2.x); a2.y = fmaf(xv.z, wv.y, a2.y); a2.z = fmaf(xv.z, wv.z, a2.z); a2.w = fmaf(xv.z, wv.w, a2.w);
    a3.x = fmaf(xv.w, wv.x, a3.x); a3.y = fmaf(xv.w, wv.y, a3.y); a3.z = fmaf(xv.w, wv.z, a3.z); a3.w = fmaf(xv.w, wv.w, a3.w);
  }
  float4 asv = *reinterpret_cast<const float4*>(&att_src[h * 64 + c0]);
  float4 adv = *reinterpret_cast<const float4*>(&att_dst[h * 64 + c0]);
#pragma unroll
  for (int rr = 0; rr < 4; ++rr) {
    float4 ar = (rr == 0) ? a0 : (rr == 1) ? a1 : (rr == 2) ? a2 : a3;
    float vs = ar.x * asv.x + ar.y * asv.y + ar.z * asv.z + ar.w * asv.w;
    float vd = ar.x * adv.x + ar.y * adv.y + ar.z * adv.z + ar.w * adv.w;
#pragma unroll
    for (int m = 1; m < 16; m <<= 1) { vs += __shfl_xor(vs, m); vd += __shfl_xor(vd, m); }
    int gr = rb + r0 + rr;
    if (gr < N_NODES) {
      if (cg == 0) { a_src[h * N_NODES + gr] = vs; a_dst[h * N_NODES + gr] = vd; }
      *reinterpret_cast<float4*>(&h1[(size_t)gr * 320 + h * 64 + c0]) = ar;
    }
  }
}

// ---- agg1: bucket CSR, 4 independent gather chains (16 edges in flight) ----

__global__ __launch_bounds__(256) void k_agg1(const float* __restrict__ h1, const float* __restrict__ a_src,
                                              const float* __restrict__ a_dst, const float* __restrict__ b1,
                                              const int* __restrict__ degs, const int* __restrict__ csr,
                                              float* __restrict__ out1) {
  int lane = threadIdx.x & 63, wid = threadIdx.x >> 6;
  int n = blockIdx.x * 4 + wid;
  int h = blockIdx.y;
  int sub = lane >> 4;        // edge slot 0..3
  int cq = lane & 15;         // channel quad
  int beg = n << 7;
  int deg = degs[n];
  int limit = beg + deg;
  int end = beg + ((deg + 15) & ~15);   // 16-padded iteration space (wave-uniform)
  const float* __restrict__ as = a_src + (size_t)h * N_NODES;
  float adn = a_dst[(size_t)h * N_NODES + n];
  const float* __restrict__ hh = h1 + h * 64 + cq * 4;
  float4 acc = make_float4(0.f, 0.f, 0.f, 0.f);
  float s = 0.f;
  int e = beg + sub;
  bool va = e < limit, vb = e + 4 < limit, vc = e + 8 < limit, vd = e + 12 < limit;
  int t0 = csr[e], t1 = csr[e + 4], t2 = csr[e + 8], t3 = csr[e + 12];
  unsigned i0 = va ? (unsigned)t0 : 0u, i1 = vb ? (unsigned)t1 : 0u;
  unsigned i2 = vc ? (unsigned)t2 : 0u, i3 = vd ? (unsigned)t3 : 0u;
  float v0 = as[i0], v1 = as[i1], v2 = as[i2], v3 = as[i3];
  for (;;) {
    float4 ga = *reinterpret_cast<const float4*>(hh + i0 * 320u);
    float4 gb = *reinterpret_cast<const float4*>(hh + i1 * 320u);
    float4 gc = *reinterpret_cast<const float4*>(hh + i2 * 320u);
    float4 gd = *reinterpret_cast<const float4*>(hh + i3 * 320u);
    float pa = va ? lrelu_exp(v0 + adn) : 0.f;
    float pb = vb ? lrelu_exp(v1 + adn) : 0.f;
    float pc = vc ? lrelu_exp(v2 + adn) : 0.f;
    float pd = vd ? lrelu_exp(v3 + adn) : 0.f;
    e += 16;
    bool more = e < end;                 // wave-uniform
    if (more) {                          // prefetch next 4 slots while gathers in flight
      va = e < limit; vb = e + 4 < limit; vc = e + 8 < limit; vd = e + 12 < limit;
      t0 = csr[e]; t1 = csr[e + 4]; t2 = csr[e + 8]; t3 = csr[e + 12];
      i0 = va ? (unsigned)t0 : 0u; i1 = vb ? (unsigned)t1 : 0u;
      i2 = vc ? (unsigned)t2 : 0u; i3 = vd ? (unsigned)t3 : 0u;
      v0 = as[i0]; v1 = as[i1]; v2 = as[i2]; v3 = as[i3];
    }
    s += (pa + pb) + (pc + pd);
    acc.x = fmaf(pd, gd.x, fmaf(pc, gc.x, fmaf(pb, gb.x, fmaf(pa, ga.x, acc.x))));
    acc.y = fmaf(pd, gd.y, fmaf(pc, gc.y, fmaf(pb, gb.y, fmaf(pa, ga.y, acc.y))));
    acc.z = fmaf(pd, gd.z, fmaf(pc, gc.z, fmaf(pb, gb.z, fmaf(pa, ga.z, acc.z))));
    acc.w = fmaf(pd, gd.w, fmaf(pc, gc.w, fmaf(pb, gb.w, fmaf(pa, ga.w, acc.w))));
    if (!more) break;
  }
#pragma unroll
  for (int m = 16; m <= 32; m <<= 1) {
    acc.x += __shfl_xor(acc.x, m);
    acc.y += __shfl_xor(acc.y, m);
    acc.z += __shfl_xor(acc.z, m);
    acc.w += __shfl_xor(acc.w, m);
    s += __shfl_xor(s, m);
  }
  if (sub == 0) {
    float inv = 1.f / (s + 1e-16f);
    const float* bp = b1 + h * 64 + cq * 4;
    float4 o;
    o.x = fmaxf(fmaf(acc.x, inv, bp[0]), 0.f);
    o.y = fmaxf(fmaf(acc.y, inv, bp[1]), 0.f);
    o.z = fmaxf(fmaf(acc.z, inv, bp[2]), 0.f);
    o.w = fmaxf(fmaf(acc.w, inv, bp[3]), 0.f);
    *reinterpret_cast<float4*>(&out1[(size_t)n * 320 + h * 64 + cq * 4]) = o;
  }
}

__global__ __launch_bounds__(256) void k_agg2(const float* __restrict__ h2, const float* __restrict__ a_src,
                                              const float* __restrict__ a_dst, const float* __restrict__ b2,
                                              const int* __restrict__ degs, const int* __restrict__ csr,
                                              float* __restrict__ out) {
  int lane = threadIdx.x & 63, wid = threadIdx.x >> 6;
  int n = blockIdx.x * 4 + wid;
  int sub = lane >> 4;
  int cq = lane & 15;
  int beg = n << 7;
  int deg = degs[n];
  int limit = beg + deg;
  int end = beg + ((deg + 15) & ~15);
  float adn = a_dst[n];
  const float* __restrict__ hh = h2 + cq * 4;
  float4 acc = make_float4(0.f, 0.f, 0.f, 0.f);
  float s = 0.f;
  int e = beg + sub;
  bool va = e < limit, vb = e + 4 < limit, vc = e + 8 < limit, vd = e + 12 < limit;
  int t0 = csr[e], t1 = csr[e + 4], t2 = csr[e + 8], t3 = csr[e + 12];
  unsigned i0 = va ? (unsigned)t0 : 0u, i1 = vb ? (unsigned)t1 : 0u;
  unsigned i2 = vc ? (unsigned)t2 : 0u, i3 = vd ? (unsigned)t3 : 0u;
  float v0 = a_src[i0], v1 = a_src[i1], v2 = a_src[i2], v3 = a_src[i3];
  for (;;) {
    float4 ga = *reinterpret_cast<const float4*>(hh + i0 * 64u);
    float4 gb = *reinterpret_cast<const float4*>(hh + i1 * 64u);
    float4 gc = *reinterpret_cast<const float4*>(hh + i2 * 64u);
    float4 gd = *reinterpret_cast<const float4*>(hh + i3 * 64u);
    float pa = va ? lrelu_exp(v0 + adn) : 0.f;
    float pb = vb ? lrelu_exp(v1 + adn) : 0.f;
    float pc = vc ? lrelu_exp(v2 + adn) : 0.f;
    float pd = vd ? lrelu_exp(v3 + adn) : 0.f;
    e += 16;
    bool more = e < end;
    if (more) {
      va = e < limit; vb = e + 4 < limit; vc = e + 8 < limit; vd = e + 12 < limit;
      t0 = csr[e]; t1 = csr[e + 4]; t2 = csr[e + 8]; t3 = csr[e + 12];
      i0 = va ? (unsigned)t0 : 0u; i1 = vb ? (unsigned)t1 : 0u;
      i2 = vc ? (unsigned)t2 : 0u; i3 = vd ? (unsigned)t3 : 0u;
      v0 = a_src[i0]; v1 = a_src[i1]; v2 = a_src[i2]; v3 = a_src[i3];
    }
    s += (pa + pb) + (pc + pd);
    acc.x = fmaf(pd, gd.x, fmaf(pc, gc.x, fmaf(pb, gb.x, fmaf(pa, ga.x, acc.x))));
    acc.y = fmaf(pd, gd.y, fmaf(pc, gc.y, fmaf(pb, gb.y, fmaf(pa, ga.y, acc.y))));
    acc.z = fmaf(pd, gd.z, fmaf(pc, gc.z, fmaf(pb, gb.z, fmaf(pa, ga.z, acc.z))));
    acc.w = fmaf(pd, gd.w, fmaf(pc, gc.w, fmaf(pb, gb.w, fmaf(pa, ga.w, acc.w))));
    if (!more) break;
  }
#pragma unroll
  for (int m = 16; m <= 32; m <<= 1) {
    acc.x += __shfl_xor(acc.x, m);
    acc.y += __shfl_xor(acc.y, m);
    acc.z += __shfl_xor(acc.z, m);
    acc.w += __shfl_xor(acc.w, m);
    s += __shfl_xor(s, m);
  }
  if (sub == 0) {
    float inv = 1.f / (s + 1e-16f);
    const float* bp = b2 + cq * 4;
    float4 o;
    o.x = fmaxf(fmaf(acc.x, inv, bp[0]), 0.f);
    o.y = fmaxf(fmaf(acc.y, inv, bp[1]), 0.f);
    o.z = fmaxf(fmaf(acc.z, inv, bp[2]), 0.f);
    o.w = fmaxf(fmaf(acc.w, inv, bp[3]), 0.f);
    *reinterpret_cast<float4*>(&out[(size_t)n * 64 + cq * 4]) = o;
  }
}

// ---- layer 2 GEMM single-pass with LDS-staged transposed W2 + fused att dots ----
// 16 rows/block, grid 625. wt[64][68]: 68-pad keeps rows 16B-aligned for b128
// reads; xs reads are wave-broadcast (conflict-free). No global loads in the
// inner loop -> no L2-latency serialization (round-11's failure mode).

__global__ __launch_bounds__(256) void k_gemm2(const float* __restrict__ out1, const float* __restrict__ W2,
                                               const float* __restrict__ att_src, const float* __restrict__ att_dst,
                                               float* __restrict__ h2, float* __restrict__ a_src,
                                               float* __restrict__ a_dst) {
  __shared__ float xs[16][320];   // 20.0 KB
  __shared__ float wt[64][68];    // 17.4 KB  (wt[c][k] = W2[kc*64+k][c])
  int t = threadIdx.x;
  int rb = blockIdx.x * 16;       // 625 * 16 = 10000 exactly
#pragma unroll
  for (int i = 0; i < 5; ++i) {
    int idx = t + 256 * i;        // 1280 float4 slots
    int row = idx / 80;
    int kq = (idx - row * 80) * 4;
    float4 v = *reinterpret_cast<const float4*>(&out1[(size_t)(rb + row) * 320 + kq]);
    *reinterpret_cast<float4*>(&xs[row][kq]) = v;
  }
  int lane = t & 63, wid = t >> 6;
  int r0 = wid * 4;
  float acc0 = 0.f, acc1 = 0.f, acc2 = 0.f, acc3 = 0.f;
  for (int kc = 0; kc < 5; ++kc) {
    __syncthreads();              // wt (and xs on first iter) safe to (re)write / fully staged
#pragma unroll
    for (int i = 0; i < 4; ++i) {
      int idx = t + 256 * i;      // 1024 float4 slots of the 64x64 W2 chunk
      int k = idx >> 4;
      int cq = (idx & 15) * 4;
      float4 v = *reinterpret_cast<const float4*>(&W2[(size_t)(kc * 64 + k) * 64 + cq]);
      wt[cq + 0][k] = v.x; wt[cq + 1][k] = v.y; wt[cq + 2][k] = v.z; wt[cq + 3][k] = v.w;
    }
    __syncthreads();
#pragma unroll
    for (int kq = 0; kq < 16; ++kq) {
      float4 w4 = *reinterpret_cast<const float4*>(&wt[lane][kq * 4]);
      float4 x0 = *reinterpret_cast<const float4*>(&xs[r0 + 0][kc * 64 + kq * 4]);
      float4 x1 = *reinterpret_cast<const float4*>(&xs[r0 + 1][kc * 64 + kq * 4]);
      float4 x2 = *reinterpret_cast<const float4*>(&xs[r0 + 2][kc * 64 + kq * 4]);
      float4 x3 = *reinterpret_cast<const float4*>(&xs[r0 + 3][kc * 64 + kq * 4]);
      acc0 = fmaf(x0.w, w4.w, fmaf(x0.z, w4.z, fmaf(x0.y, w4.y, fmaf(x0.x, w4.x, acc0))));
      acc1 = fmaf(x1.w, w4.w, fmaf(x1.z, w4.z, fmaf(x1.y, w4.y, fmaf(x1.x, w4.x, acc1))));
      acc2 = fmaf(x2.w, w4.w, fmaf(x2.z, w4.z, fmaf(x2.y, w4.y, fmaf(x2.x, w4.x, acc2))));
      acc3 = fmaf(x3.w, w4.w, fmaf(x3.z, w4.z, fmaf(x3.y, w4.y, fmaf(x3.x, w4.x, acc3))));
    }
  }
  float as = att_src[lane], ad = att_dst[lane];
#pragma unroll
  for (int rr = 0; rr < 4; ++rr) {
    float a = (rr == 0) ? acc0 : (rr == 1) ? acc1 : (rr == 2) ? acc2 : acc3;
    float vs = a * as, vd = a * ad;
#pragma unroll
    for (int m = 1; m < 64; m <<= 1) { vs += __shfl_xor(vs, m); vd += __shfl_xor(vd, m); }
    int gr = rb + r0 + rr;
    h2[(size_t)gr * 64 + lane] = a;
    if (lane == 0) { a_src[gr] = vs; a_dst[gr] = vd; }
  }
}

// ---------------- launch ----------------

extern "C" void kernel_launch(void* const* d_in, const int* in_sizes, int n_in,
                              void* d_out, int out_size, void* d_ws, size_t ws_size,
                              hipStream_t stream) {
  (void)in_sizes; (void)n_in; (void)out_size; (void)ws_size;
  const float* x    = (const float*)d_in[0];
  const int*   ei   = (const int*)d_in[1];
  const float* W1   = (const float*)d_in[2];
  const float* as1w = (const float*)d_in[3];
  const float* ad1w = (const float*)d_in[4];
  const float* b1   = (const float*)d_in[5];
  const float* W2   = (const float*)d_in[6];
  const float* as2w = (const float*)d_in[7];
  const float* ad2w = (const float*)d_in[8];
  const float* b2   = (const float*)d_in[9];
  float* out = (float*)d_out;

  char* ws = (char*)d_ws;
  size_t off = 0;
  auto alloc = [&](size_t bytes) -> void* {
    void* p = ws + off;
    off += (bytes + 255) & ~(size_t)255;
    return p;
  };
  float*  h1     = (float*)alloc((size_t)N_NODES * 320 * 4);
  float*  out1   = (float*)alloc((size_t)N_NODES * 320 * 4);
  float*  h2     = (float*)alloc((size_t)N_NODES * 64 * 4);
  float*  a_src1 = (float*)alloc((size_t)5 * N_NODES * 4);
  float*  a_dst1 = (float*)alloc((size_t)5 * N_NODES * 4);
  float*  a_src2 = (float*)alloc((size_t)N_NODES * 4);
  float*  a_dst2 = (float*)alloc((size_t)N_NODES * 4);
  int*    cursor = (int*)alloc((size_t)N_NODES * 4);
  int*    csr    = (int*)alloc((size_t)N_NODES * CAP * 4);  // pad slots never interpreted: no init

  k_init<<<(N_NODES + 255) / 256, 256, 0, stream>>>(cursor);
  k_gemm1_scatter<<<NB_G1 + NB_SCT, 256, 0, stream>>>(x, W1, as1w, ad1w, h1, a_src1, a_dst1,
                                                      ei, cursor, csr);
  {
    dim3 g(N_NODES / 4, 5);
    k_agg1 <<<g, 256, 0, stream>>>(h1, a_src1, a_dst1, b1, cursor, csr, out1);
  }
  k_gemm2<<<N_NODES / 16, 256, 0, stream>>>(out1, W2, as2w, ad2w, h2, a_src2, a_dst2);
  k_agg2 <<<N_NODES / 4, 256, 0, stream>>>(h2, a_src2, a_dst2, b2, cursor, csr, out);
}

// Round 14
// 100.956 us; speedup vs baseline: 4.1711x; 1.1294x over previous
//
#include <hip/hip_runtime.h>
#include <hip/hip_fp16.h>
#include <math.h>

#define N_NODES 10000
#define N_EDGES 320000
#define ET (N_EDGES + N_NODES)        // edges + self-loops
#define CAP 128                       // per-node CSR bucket capacity (max deg ~60)
#define NB_G1 (157 * 5)               // gemm1 blocks in fused launch
#define NB_SCT ((ET + 255) / 256)     // scatter blocks in fused launch

__device__ __forceinline__ float lrelu_exp(float e) {
  e = (e > 0.f) ? e : 0.2f * e;   // leaky_relu
  return __expf(e);               // logits O(+-6): no max-shift needed
}

__device__ __forceinline__ float4 ld_half4(const __half* p) {
  uint2 u = *reinterpret_cast<const uint2*>(p);
  float2 f0 = __half22float2(*reinterpret_cast<const __half2*>(&u.x));
  float2 f1 = __half22float2(*reinterpret_cast<const __half2*>(&u.y));
  return make_float4(f0.x, f0.y, f1.x, f1.y);
}

__device__ __forceinline__ void st_half4(__half* p, float4 v) {
  __half2 lo = __float22half2_rn(make_float2(v.x, v.y));
  __half2 hi = __float22half2_rn(make_float2(v.z, v.w));
  uint2 u;
  u.x = *reinterpret_cast<const unsigned*>(&lo);
  u.y = *reinterpret_cast<const unsigned*>(&hi);
  *reinterpret_cast<uint2*>(p) = u;
}

// ---------------- init: zero cursor ----------------

__global__ __launch_bounds__(256) void k_init(int* __restrict__ cursor) {
  int i = blockIdx.x * 256 + threadIdx.x;
  if (i < N_NODES) cursor[i] = 0;
}

// ------- fused: gemm1 (blocks 0..784, h1 out in fp16) + bucket-scatter (rest) -------

__global__ __launch_bounds__(256) void k_gemm1_scatter(const float* __restrict__ x, const float* __restrict__ W1,
                                                       const float* __restrict__ att_src, const float* __restrict__ att_dst,
                                                       __half* __restrict__ h1, float* __restrict__ a_src,
                                                       float* __restrict__ a_dst,
                                                       const int* __restrict__ ei, int* __restrict__ cursor,
                                                       int* __restrict__ csr) {
  __shared__ float xs[128][65];
  int bid = blockIdx.x;
  int t = threadIdx.x;
  if (bid >= NB_G1) {                      // ---- scatter path ----
    int i = (bid - NB_G1) * 256 + t;
    if (i < ET) {
      int src, dst;
      if (i < N_EDGES) { src = ei[i]; dst = ei[N_EDGES + i]; }
      else             { src = dst = i - N_EDGES; }
      int pos = (dst << 7) + atomicAdd(&cursor[dst], 1);
      csr[pos] = src;
    }
    return;
  }
  // ---- gemm1 path: 64-row x 64-col tile, head = bid/157 ----
  int h = bid / 157;
  int rb = (bid % 157) * 64;
#pragma unroll
  for (int i = 0; i < 8; ++i) {
    int idx = t + 256 * i;
    int kq = (idx & 31) * 4;
    int row = idx >> 5;
    int gr = rb + row;
    float4 v = make_float4(0.f, 0.f, 0.f, 0.f);
    if (gr < N_NODES) v = *reinterpret_cast<const float4*>(&x[(size_t)gr * 128 + kq]);
    xs[kq + 0][row] = v.x; xs[kq + 1][row] = v.y; xs[kq + 2][row] = v.z; xs[kq + 3][row] = v.w;
  }
  __syncthreads();
  int cg = t & 15, rg = t >> 4;
  int c0 = cg * 4, r0 = rg * 4;
  const float* __restrict__ wp = W1 + h * 64 + c0;
  float4 a0 = make_float4(0.f,0.f,0.f,0.f), a1 = a0, a2 = a0, a3 = a0;
#pragma unroll 4
  for (int k = 0; k < 128; ++k) {
    float4 xv = *reinterpret_cast<const float4*>(&xs[k][r0]);
    float4 wv = *reinterpret_cast<const float4*>(&wp[(size_t)k * 320]);
    a0.x = fmaf(xv.x, wv.x, a0.x); a0.y = fmaf(xv.x, wv.y, a0.y); a0.z = fmaf(xv.x, wv.z, a0.z); a0.w = fmaf(xv.x, wv.w, a0.w);
    a1.x = fmaf(xv.y, wv.x, a1.x); a1.y = fmaf(xv.y, wv.y, a1.y); a1.z = fmaf(xv.y, wv.z, a1.z); a1.w = fmaf(xv.y, wv.w, a1.w);
    a2.x = fmaf(xv.z, wv.x, a2.x); a2.y = fmaf(xv.z, wv.y, a2.y); a2.z = fmaf(xv.z, wv.z, a2.z); a2.w = fmaf(xv.z, wv.w, a2.w);
    a3.x = fmaf(xv.w, wv.x, a3.x); a3.y = fmaf(xv.w, wv.y, a3.y); a3.z = fmaf(xv.w, wv.z, a3.z); a3.w = fmaf(xv.w, wv.w, a3.w);
  }
  float4 asv = *reinterpret_cast<const float4*>(&att_src[h * 64 + c0]);
  float4 adv = *reinterpret_cast<const float4*>(&att_dst[h * 64 + c0]);
#pragma unroll
  for (int rr = 0; rr < 4; ++rr) {
    float4 ar = (rr == 0) ? a0 : (rr == 1) ? a1 : (rr == 2) ? a2 : a3;
    float vs = ar.x * asv.x + ar.y * asv.y + ar.z * asv.z + ar.w * asv.w;
    float vd = ar.x * adv.x + ar.y * adv.y + ar.z * adv.z + ar.w * adv.w;
#pragma unroll
    for (int m = 1; m < 16; m <<= 1) { vs += __shfl_xor(vs, m); vd += __shfl_xor(vd, m); }
    int gr = rb + r0 + rr;
    if (gr < N_NODES) {
      if (cg == 0) { a_src[h * N_NODES + gr] = vs; a_dst[h * N_NODES + gr] = vd; }
      st_half4(&h1[(size_t)gr * 320 + h * 64 + c0], ar);   // fp16 storage: 128B/head-row
    }
  }
}

// ---- agg1: bucket CSR, 4 chains, fp16 gathers (1 cache line per edge) ----

__global__ __launch_bounds__(256) void k_agg1(const __half* __restrict__ h1, const float* __restrict__ a_src,
                                              const float* __restrict__ a_dst, const float* __restrict__ b1,
                                              const int* __restrict__ degs, const int* __restrict__ csr,
                                              float* __restrict__ out1) {
  int lane = threadIdx.x & 63, wid = threadIdx.x >> 6;
  int n = blockIdx.x * 4 + wid;
  int h = blockIdx.y;
  int sub = lane >> 4;        // edge slot 0..3
  int cq = lane & 15;         // channel quad
  int beg = n << 7;
  int deg = degs[n];
  int limit = beg + deg;
  int end = beg + ((deg + 15) & ~15);   // 16-padded iteration space (wave-uniform)
  const float* __restrict__ as = a_src + (size_t)h * N_NODES;
  float adn = a_dst[(size_t)h * N_NODES + n];
  const __half* __restrict__ hh = h1 + h * 64 + cq * 4;
  float4 acc = make_float4(0.f, 0.f, 0.f, 0.f);
  float s = 0.f;
  int e = beg + sub;
  bool va = e < limit, vb = e + 4 < limit, vc = e + 8 < limit, vd = e + 12 < limit;
  int t0 = csr[e], t1 = csr[e + 4], t2 = csr[e + 8], t3 = csr[e + 12];
  unsigned i0 = va ? (unsigned)t0 : 0u, i1 = vb ? (unsigned)t1 : 0u;
  unsigned i2 = vc ? (unsigned)t2 : 0u, i3 = vd ? (unsigned)t3 : 0u;
  float v0 = as[i0], v1 = as[i1], v2 = as[i2], v3 = as[i3];
  for (;;) {
    float4 ga = ld_half4(hh + i0 * 320u);
    float4 gb = ld_half4(hh + i1 * 320u);
    float4 gc = ld_half4(hh + i2 * 320u);
    float4 gd = ld_half4(hh + i3 * 320u);
    float pa = va ? lrelu_exp(v0 + adn) : 0.f;
    float pb = vb ? lrelu_exp(v1 + adn) : 0.f;
    float pc = vc ? lrelu_exp(v2 + adn) : 0.f;
    float pd = vd ? lrelu_exp(v3 + adn) : 0.f;
    e += 16;
    bool more = e < end;                 // wave-uniform
    if (more) {                          // prefetch next 4 slots while gathers in flight
      va = e < limit; vb = e + 4 < limit; vc = e + 8 < limit; vd = e + 12 < limit;
      t0 = csr[e]; t1 = csr[e + 4]; t2 = csr[e + 8]; t3 = csr[e + 12];
      i0 = va ? (unsigned)t0 : 0u; i1 = vb ? (unsigned)t1 : 0u;
      i2 = vc ? (unsigned)t2 : 0u; i3 = vd ? (unsigned)t3 : 0u;
      v0 = as[i0]; v1 = as[i1]; v2 = as[i2]; v3 = as[i3];
    }
    s += (pa + pb) + (pc + pd);
    acc.x = fmaf(pd, gd.x, fmaf(pc, gc.x, fmaf(pb, gb.x, fmaf(pa, ga.x, acc.x))));
    acc.y = fmaf(pd, gd.y, fmaf(pc, gc.y, fmaf(pb, gb.y, fmaf(pa, ga.y, acc.y))));
    acc.z = fmaf(pd, gd.z, fmaf(pc, gc.z, fmaf(pb, gb.z, fmaf(pa, ga.z, acc.z))));
    acc.w = fmaf(pd, gd.w, fmaf(pc, gc.w, fmaf(pb, gb.w, fmaf(pa, ga.w, acc.w))));
    if (!more) break;
  }
#pragma unroll
  for (int m = 16; m <= 32; m <<= 1) {
    acc.x += __shfl_xor(acc.x, m);
    acc.y += __shfl_xor(acc.y, m);
    acc.z += __shfl_xor(acc.z, m);
    acc.w += __shfl_xor(acc.w, m);
    s += __shfl_xor(s, m);
  }
  if (sub == 0) {
    float inv = 1.f / (s + 1e-16f);
    const float* bp = b1 + h * 64 + cq * 4;
    float4 o;
    o.x = fmaxf(fmaf(acc.x, inv, bp[0]), 0.f);
    o.y = fmaxf(fmaf(acc.y, inv, bp[1]), 0.f);
    o.z = fmaxf(fmaf(acc.z, inv, bp[2]), 0.f);
    o.w = fmaxf(fmaf(acc.w, inv, bp[3]), 0.f);
    *reinterpret_cast<float4*>(&out1[(size_t)n * 320 + h * 64 + cq * 4]) = o;
  }
}

__global__ __launch_bounds__(256) void k_agg2(const __half* __restrict__ h2, const float* __restrict__ a_src,
                                              const float* __restrict__ a_dst, const float* __restrict__ b2,
                                              const int* __restrict__ degs, const int* __restrict__ csr,
                                              float* __restrict__ out) {
  int lane = threadIdx.x & 63, wid = threadIdx.x >> 6;
  int n = blockIdx.x * 4 + wid;
  int sub = lane >> 4;
  int cq = lane & 15;
  int beg = n << 7;
  int deg = degs[n];
  int limit = beg + deg;
  int end = beg + ((deg + 15) & ~15);
  float adn = a_dst[n];
  const __half* __restrict__ hh = h2 + cq * 4;
  float4 acc = make_float4(0.f, 0.f, 0.f, 0.f);
  float s = 0.f;
  int e = beg + sub;
  bool va = e < limit, vb = e + 4 < limit, vc = e + 8 < limit, vd = e + 12 < limit;
  int t0 = csr[e], t1 = csr[e + 4], t2 = csr[e + 8], t3 = csr[e + 12];
  unsigned i0 = va ? (unsigned)t0 : 0u, i1 = vb ? (unsigned)t1 : 0u;
  unsigned i2 = vc ? (unsigned)t2 : 0u, i3 = vd ? (unsigned)t3 : 0u;
  float v0 = a_src[i0], v1 = a_src[i1], v2 = a_src[i2], v3 = a_src[i3];
  for (;;) {
    float4 ga = ld_half4(hh + i0 * 64u);
    float4 gb = ld_half4(hh + i1 * 64u);
    float4 gc = ld_half4(hh + i2 * 64u);
    float4 gd = ld_half4(hh + i3 * 64u);
    float pa = va ? lrelu_exp(v0 + adn) : 0.f;
    float pb = vb ? lrelu_exp(v1 + adn) : 0.f;
    float pc = vc ? lrelu_exp(v2 + adn) : 0.f;
    float pd = vd ? lrelu_exp(v3 + adn) : 0.f;
    e += 16;
    bool more = e < end;
    if (more) {
      va = e < limit; vb = e + 4 < limit; vc = e + 8 < limit; vd = e + 12 < limit;
      t0 = csr[e]; t1 = csr[e + 4]; t2 = csr[e + 8]; t3 = csr[e + 12];
      i0 = va ? (unsigned)t0 : 0u; i1 = vb ? (unsigned)t1 : 0u;
      i2 = vc ? (unsigned)t2 : 0u; i3 = vd ? (unsigned)t3 : 0u;
      v0 = a_src[i0]; v1 = a_src[i1]; v2 = a_src[i2]; v3 = a_src[i3];
    }
    s += (pa + pb) + (pc + pd);
    acc.x = fmaf(pd, gd.x, fmaf(pc, gc.x, fmaf(pb, gb.x, fmaf(pa, ga.x, acc.x))));
    acc.y = fmaf(pd, gd.y, fmaf(pc, gc.y, fmaf(pb, gb.y, fmaf(pa, ga.y, acc.y))));
    acc.z = fmaf(pd, gd.z, fmaf(pc, gc.z, fmaf(pb, gb.z, fmaf(pa, ga.z, acc.z))));
    acc.w = fmaf(pd, gd.w, fmaf(pc, gc.w, fmaf(pb, gb.w, fmaf(pa, ga.w, acc.w))));
    if (!more) break;
  }
#pragma unroll
  for (int m = 16; m <= 32; m <<= 1) {
    acc.x += __shfl_xor(acc.x, m);
    acc.y += __shfl_xor(acc.y, m);
    acc.z += __shfl_xor(acc.z, m);
    acc.w += __shfl_xor(acc.w, m);
    s += __shfl_xor(s, m);
  }
  if (sub == 0) {
    float inv = 1.f / (s + 1e-16f);
    const float* bp = b2 + cq * 4;
    float4 o;
    o.x = fmaxf(fmaf(acc.x, inv, bp[0]), 0.f);
    o.y = fmaxf(fmaf(acc.y, inv, bp[1]), 0.f);
    o.z = fmaxf(fmaf(acc.z, inv, bp[2]), 0.f);
    o.w = fmaxf(fmaf(acc.w, inv, bp[3]), 0.f);
    *reinterpret_cast<float4*>(&out[(size_t)n * 64 + cq * 4]) = o;
  }
}

// ---- layer 2 GEMM: split-K, blockIdx.y = K-chunk (grid 157x5), partials out ----

__global__ __launch_bounds__(256) void k_gemm2(const float* __restrict__ out1, const float* __restrict__ W2,
                                               float* __restrict__ h2part) {
  __shared__ float xs[64][65];
  int t = threadIdx.x;
  int rb = blockIdx.x * 64;
  int kc = blockIdx.y;
#pragma unroll
  for (int i = 0; i < 4; ++i) {
    int idx = t + 256 * i;
    int kq = (idx & 15) * 4;
    int row = idx >> 4;
    int gr = rb + row;
    float4 v = make_float4(0.f, 0.f, 0.f, 0.f);
    if (gr < N_NODES) v = *reinterpret_cast<const float4*>(&out1[(size_t)gr * 320 + kc * 64 + kq]);
    xs[kq + 0][row] = v.x; xs[kq + 1][row] = v.y; xs[kq + 2][row] = v.z; xs[kq + 3][row] = v.w;
  }
  __syncthreads();
  int cg = t & 15, rg = t >> 4;
  int c0 = cg * 4, r0 = rg * 4;
  const float* __restrict__ wp = W2 + (size_t)kc * 64 * 64 + c0;
  float4 a0 = make_float4(0.f,0.f,0.f,0.f), a1 = a0, a2 = a0, a3 = a0;
#pragma unroll 4
  for (int k = 0; k < 64; ++k) {
    float4 xv = *reinterpret_cast<const float4*>(&xs[k][r0]);
    float4 wv = *reinterpret_cast<const float4*>(&wp[(size_t)k * 64]);
    a0.x = fmaf(xv.x, wv.x, a0.x); a0.y = fmaf(xv.x, wv.y, a0.y); a0.z = fmaf(xv.x, wv.z, a0.z); a0.w = fmaf(xv.x, wv.w, a0.w);
    a1.x = fmaf(xv.y, wv.x, a1.x); a1.y = fmaf(xv.y, wv.y, a1.y); a1.z = fmaf(xv.y, wv.z, a1.z); a1.w = fmaf(xv.y, wv.w, a1.w);
    a2.x = fmaf(xv.z, wv.x, a2.x); a2.y = fmaf(xv.z, wv.y, a2.y); a2.z = fmaf(xv.z, wv.z, a2.z); a2.w = fmaf(xv.z, wv.w, a2.w);
    a3.x = fmaf(xv.w, wv.x, a3.x); a3.y = fmaf(xv.w, wv.y, a3.y); a3.z = fmaf(xv.w, wv.z, a3.z); a3.w = fmaf(xv.w, wv.w, a3.w);
  }
  float* __restrict__ hp = h2part + (size_t)kc * N_NODES * 64;
#pragma unroll
  for (int rr = 0; rr < 4; ++rr) {
    float4 ar = (rr == 0) ? a0 : (rr == 1) ? a1 : (rr == 2) ? a2 : a3;
    int gr = rb + r0 + rr;
    if (gr < N_NODES) *reinterpret_cast<float4*>(&hp[(size_t)gr * 64 + c0]) = ar;
  }
}

// ---- reduce 5 partials (fixed order) + att dots; h2 stored fp16 ----

__global__ __launch_bounds__(256) void k_hred2(const float* __restrict__ h2part,
                                               const float* __restrict__ att_src, const float* __restrict__ att_dst,
                                               __half* __restrict__ h2, float* __restrict__ a_src,
                                               float* __restrict__ a_dst) {
  int n = blockIdx.x * 4 + (threadIdx.x >> 6);
  int c = threadIdx.x & 63;
  if (n >= N_NODES) return;
  float v = 0.f;
#pragma unroll
  for (int kc = 0; kc < 5; ++kc) v += h2part[((size_t)kc * N_NODES + n) * 64 + c];
  float vs = v * att_src[c], vd = v * att_dst[c];
  float vnext = __shfl_down(v, 1);
  if ((c & 1) == 0) {
    __half2 p = __float22half2_rn(make_float2(v, vnext));
    *reinterpret_cast<unsigned*>(&h2[(size_t)n * 64 + c]) = *reinterpret_cast<const unsigned*>(&p);
  }
  for (int off = 32; off; off >>= 1) {
    vs += __shfl_down(vs, off);
    vd += __shfl_down(vd, off);
  }
  if (c == 0) { a_src[n] = vs; a_dst[n] = vd; }
}

// ---------------- launch ----------------

extern "C" void kernel_launch(void* const* d_in, const int* in_sizes, int n_in,
                              void* d_out, int out_size, void* d_ws, size_t ws_size,
                              hipStream_t stream) {
  (void)in_sizes; (void)n_in; (void)out_size; (void)ws_size;
  const float* x    = (const float*)d_in[0];
  const int*   ei   = (const int*)d_in[1];
  const float* W1   = (const float*)d_in[2];
  const float* as1w = (const float*)d_in[3];
  const float* ad1w = (const float*)d_in[4];
  const float* b1   = (const float*)d_in[5];
  const float* W2   = (const float*)d_in[6];
  const float* as2w = (const float*)d_in[7];
  const float* ad2w = (const float*)d_in[8];
  const float* b2   = (const float*)d_in[9];
  float* out = (float*)d_out;

  char* ws = (char*)d_ws;
  size_t off = 0;
  auto alloc = [&](size_t bytes) -> void* {
    void* p = ws + off;
    off += (bytes + 255) & ~(size_t)255;
    return p;
  };
  __half* h1     = (__half*)alloc((size_t)N_NODES * 320 * 2);
  float*  out1   = (float*)alloc((size_t)N_NODES * 320 * 4);
  __half* h2     = (__half*)alloc((size_t)N_NODES * 64 * 2);
  float*  h2part = (float*)alloc((size_t)5 * N_NODES * 64 * 4);
  float*  a_src1 = (float*)alloc((size_t)5 * N_NODES * 4);
  float*  a_dst1 = (float*)alloc((size_t)5 * N_NODES * 4);
  float*  a_src2 = (float*)alloc((size_t)N_NODES * 4);
  float*  a_dst2 = (float*)alloc((size_t)N_NODES * 4);
  int*    cursor = (int*)alloc((size_t)N_NODES * 4);
  int*    csr    = (int*)alloc((size_t)N_NODES * CAP * 4);  // pad slots never interpreted: no init

  k_init<<<(N_NODES + 255) / 256, 256, 0, stream>>>(cursor);
  k_gemm1_scatter<<<NB_G1 + NB_SCT, 256, 0, stream>>>(x, W1, as1w, ad1w, h1, a_src1, a_dst1,
                                                      ei, cursor, csr);
  {
    dim3 g(N_NODES / 4, 5);
    k_agg1 <<<g, 256, 0, stream>>>(h1, a_src1, a_dst1, b1, cursor, csr, out1);
  }
  {
    dim3 g((N_NODES + 63) / 64, 5);
    k_gemm2<<<g, 256, 0, stream>>>(out1, W2, h2part);
  }
  k_hred2<<<(N_NODES + 3) / 4, 256, 0, stream>>>(h2part, as2w, ad2w, h2, a_src2, a_dst2);
  k_agg2 <<<N_NODES / 4, 256, 0, stream>>>(h2, a_src2, a_dst2, b2, cursor, csr, out);
}

// Round 15
// 96.883 us; speedup vs baseline: 4.3464x; 1.0420x over previous
//
#include <hip/hip_runtime.h>
#include <hip/hip_fp16.h>
#include <math.h>

#define N_NODES 10000
#define N_EDGES 320000
#define ET (N_EDGES + N_NODES)        // edges + self-loops
#define CAP 128                       // per-node CSR bucket capacity (max deg ~60)
#define NB_G1 (157 * 5)               // gemm1 blocks in fused launch
#define NB_SCT ((ET + 255) / 256)     // scatter blocks in fused launch

__device__ __forceinline__ float lrelu_exp(float e) {
  e = (e > 0.f) ? e : 0.2f * e;   // leaky_relu
  return __expf(e);               // logits O(+-6): no max-shift needed
}

__device__ __forceinline__ void ld_half8(const __half* p, float4& lo, float4& hi) {
  uint4 u = *reinterpret_cast<const uint4*>(p);   // 16B: one line-segment per edge-row
  float2 f0 = __half22float2(*reinterpret_cast<const __half2*>(&u.x));
  float2 f1 = __half22float2(*reinterpret_cast<const __half2*>(&u.y));
  float2 f2 = __half22float2(*reinterpret_cast<const __half2*>(&u.z));
  float2 f3 = __half22float2(*reinterpret_cast<const __half2*>(&u.w));
  lo = make_float4(f0.x, f0.y, f1.x, f1.y);
  hi = make_float4(f2.x, f2.y, f3.x, f3.y);
}

__device__ __forceinline__ void st_half4(__half* p, float4 v) {
  __half2 lo = __float22half2_rn(make_float2(v.x, v.y));
  __half2 hi = __float22half2_rn(make_float2(v.z, v.w));
  uint2 u;
  u.x = *reinterpret_cast<const unsigned*>(&lo);
  u.y = *reinterpret_cast<const unsigned*>(&hi);
  *reinterpret_cast<uint2*>(p) = u;
}

// ---------------- init: zero cursor ----------------

__global__ __launch_bounds__(256) void k_init(int* __restrict__ cursor) {
  int i = blockIdx.x * 256 + threadIdx.x;
  if (i < N_NODES) cursor[i] = 0;
}

// ------- fused: gemm1 (blocks 0..784, h1 out in fp16) + bucket-scatter (rest) -------

__global__ __launch_bounds__(256) void k_gemm1_scatter(const float* __restrict__ x, const float* __restrict__ W1,
                                                       const float* __restrict__ att_src, const float* __restrict__ att_dst,
                                                       __half* __restrict__ h1, float* __restrict__ a_src,
                                                       float* __restrict__ a_dst,
                                                       const int* __restrict__ ei, int* __restrict__ cursor,
                                                       int* __restrict__ csr) {
  __shared__ float xs[128][65];
  int bid = blockIdx.x;
  int t = threadIdx.x;
  if (bid >= NB_G1) {                      // ---- scatter path ----
    int i = (bid - NB_G1) * 256 + t;
    if (i < ET) {
      int src, dst;
      if (i < N_EDGES) { src = ei[i]; dst = ei[N_EDGES + i]; }
      else             { src = dst = i - N_EDGES; }
      int pos = (dst << 7) + atomicAdd(&cursor[dst], 1);
      csr[pos] = src;
    }
    return;
  }
  // ---- gemm1 path: 64-row x 64-col tile, head = bid/157 ----
  int h = bid / 157;
  int rb = (bid % 157) * 64;
#pragma unroll
  for (int i = 0; i < 8; ++i) {
    int idx = t + 256 * i;
    int kq = (idx & 31) * 4;
    int row = idx >> 5;
    int gr = rb + row;
    float4 v = make_float4(0.f, 0.f, 0.f, 0.f);
    if (gr < N_NODES) v = *reinterpret_cast<const float4*>(&x[(size_t)gr * 128 + kq]);
    xs[kq + 0][row] = v.x; xs[kq + 1][row] = v.y; xs[kq + 2][row] = v.z; xs[kq + 3][row] = v.w;
  }
  __syncthreads();
  int cg = t & 15, rg = t >> 4;
  int c0 = cg * 4, r0 = rg * 4;
  const float* __restrict__ wp = W1 + h * 64 + c0;
  float4 a0 = make_float4(0.f,0.f,0.f,0.f), a1 = a0, a2 = a0, a3 = a0;
#pragma unroll 4
  for (int k = 0; k < 128; ++k) {
    float4 xv = *reinterpret_cast<const float4*>(&xs[k][r0]);
    float4 wv = *reinterpret_cast<const float4*>(&wp[(size_t)k * 320]);
    a0.x = fmaf(xv.x, wv.x, a0.x); a0.y = fmaf(xv.x, wv.y, a0.y); a0.z = fmaf(xv.x, wv.z, a0.z); a0.w = fmaf(xv.x, wv.w, a0.w);
    a1.x = fmaf(xv.y, wv.x, a1.x); a1.y = fmaf(xv.y, wv.y, a1.y); a1.z = fmaf(xv.y, wv.z, a1.z); a1.w = fmaf(xv.y, wv.w, a1.w);
    a2.x = fmaf(xv.z, wv.x, a2.x); a2.y = fmaf(xv.z, wv.y, a2.y); a2.z = fmaf(xv.z, wv.z, a2.z); a2.w = fmaf(xv.z, wv.w, a2.w);
    a3.x = fmaf(xv.w, wv.x, a3.x); a3.y = fmaf(xv.w, wv.y, a3.y); a3.z = fmaf(xv.w, wv.z, a3.z); a3.w = fmaf(xv.w, wv.w, a3.w);
  }
  float4 asv = *reinterpret_cast<const float4*>(&att_src[h * 64 + c0]);
  float4 adv = *reinterpret_cast<const float4*>(&att_dst[h * 64 + c0]);
#pragma unroll
  for (int rr = 0; rr < 4; ++rr) {
    float4 ar = (rr == 0) ? a0 : (rr == 1) ? a1 : (rr == 2) ? a2 : a3;
    float vs = ar.x * asv.x + ar.y * asv.y + ar.z * asv.z + ar.w * asv.w;
    float vd = ar.x * adv.x + ar.y * adv.y + ar.z * adv.z + ar.w * adv.w;
#pragma unroll
    for (int m = 1; m < 16; m <<= 1) { vs += __shfl_xor(vs, m); vd += __shfl_xor(vd, m); }
    int gr = rb + r0 + rr;
    if (gr < N_NODES) {
      if (cg == 0) { a_src[h * N_NODES + gr] = vs; a_dst[h * N_NODES + gr] = vd; }
      st_half4(&h1[(size_t)gr * 320 + h * 64 + c0], ar);   // fp16 storage: 128B/head-row
    }
  }
}

// ---- agg1: 8 edge-slots x 8 lanes/edge, 16B fp16 gathers (1 instr = 8 edges) ----

__global__ __launch_bounds__(256) void k_agg1(const __half* __restrict__ h1, const float* __restrict__ a_src,
                                              const float* __restrict__ a_dst, const float* __restrict__ b1,
                                              const int* __restrict__ degs, const int* __restrict__ csr,
                                              float* __restrict__ out1) {
  int lane = threadIdx.x & 63, wid = threadIdx.x >> 6;
  int n = blockIdx.x * 4 + wid;
  int h = blockIdx.y;
  int sub = lane >> 3;        // edge slot 0..7
  int cg = lane & 7;          // channel octet
  int beg = n << 7;
  int deg = degs[n];
  int limit = beg + deg;
  int end = beg + ((deg + 15) & ~15);   // 16-padded iteration space (wave-uniform)
  const float* __restrict__ as = a_src + (size_t)h * N_NODES;
  float adn = a_dst[(size_t)h * N_NODES + n];
  const __half* __restrict__ hh = h1 + h * 64 + cg * 8;
  float4 aclo = make_float4(0.f, 0.f, 0.f, 0.f), achi = aclo;
  float s = 0.f;
  int e = beg + sub;
  bool va = e < limit, vb = e + 8 < limit;
  int t0 = csr[e], t1 = csr[e + 8];
  unsigned i0 = va ? (unsigned)t0 : 0u, i1 = vb ? (unsigned)t1 : 0u;
  float v0 = as[i0], v1 = as[i1];
  for (;;) {
    float4 galo, gahi, gblo, gbhi;
    ld_half8(hh + i0 * 320u, galo, gahi);
    ld_half8(hh + i1 * 320u, gblo, gbhi);
    float pa = va ? lrelu_exp(v0 + adn) : 0.f;
    float pb = vb ? lrelu_exp(v1 + adn) : 0.f;
    e += 16;
    bool more = e < end;                 // wave-uniform
    if (more) {                          // prefetch next slots while gathers in flight
      va = e < limit; vb = e + 8 < limit;
      t0 = csr[e]; t1 = csr[e + 8];
      i0 = va ? (unsigned)t0 : 0u; i1 = vb ? (unsigned)t1 : 0u;
      v0 = as[i0]; v1 = as[i1];
    }
    s += pa + pb;
    aclo.x = fmaf(pb, gblo.x, fmaf(pa, galo.x, aclo.x));
    aclo.y = fmaf(pb, gblo.y, fmaf(pa, galo.y, aclo.y));
    aclo.z = fmaf(pb, gblo.z, fmaf(pa, galo.z, aclo.z));
    aclo.w = fmaf(pb, gblo.w, fmaf(pa, galo.w, aclo.w));
    achi.x = fmaf(pb, gbhi.x, fmaf(pa, gahi.x, achi.x));
    achi.y = fmaf(pb, gbhi.y, fmaf(pa, gahi.y, achi.y));
    achi.z = fmaf(pb, gbhi.z, fmaf(pa, gahi.z, achi.z));
    achi.w = fmaf(pb, gbhi.w, fmaf(pa, gahi.w, achi.w));
    if (!more) break;
  }
#pragma unroll
  for (int m = 8; m <= 32; m <<= 1) {    // reduce across 8 edge-slots
    aclo.x += __shfl_xor(aclo.x, m);
    aclo.y += __shfl_xor(aclo.y, m);
    aclo.z += __shfl_xor(aclo.z, m);
    aclo.w += __shfl_xor(aclo.w, m);
    achi.x += __shfl_xor(achi.x, m);
    achi.y += __shfl_xor(achi.y, m);
    achi.z += __shfl_xor(achi.z, m);
    achi.w += __shfl_xor(achi.w, m);
    s += __shfl_xor(s, m);
  }
  if (sub == 0) {
    float inv = 1.f / (s + 1e-16f);
    const float* bp = b1 + h * 64 + cg * 8;
    float4 b_lo = *reinterpret_cast<const float4*>(bp);
    float4 b_hi = *reinterpret_cast<const float4*>(bp + 4);
    float4 olo, ohi;
    olo.x = fmaxf(fmaf(aclo.x, inv, b_lo.x), 0.f);
    olo.y = fmaxf(fmaf(aclo.y, inv, b_lo.y), 0.f);
    olo.z = fmaxf(fmaf(aclo.z, inv, b_lo.z), 0.f);
    olo.w = fmaxf(fmaf(aclo.w, inv, b_lo.w), 0.f);
    ohi.x = fmaxf(fmaf(achi.x, inv, b_hi.x), 0.f);
    ohi.y = fmaxf(fmaf(achi.y, inv, b_hi.y), 0.f);
    ohi.z = fmaxf(fmaf(achi.z, inv, b_hi.z), 0.f);
    ohi.w = fmaxf(fmaf(achi.w, inv, b_hi.w), 0.f);
    float* op = &out1[(size_t)n * 320 + h * 64 + cg * 8];
    *reinterpret_cast<float4*>(op) = olo;
    *reinterpret_cast<float4*>(op + 4) = ohi;
  }
}

__global__ __launch_bounds__(256) void k_agg2(const __half* __restrict__ h2, const float* __restrict__ a_src,
                                              const float* __restrict__ a_dst, const float* __restrict__ b2,
                                              const int* __restrict__ degs, const int* __restrict__ csr,
                                              float* __restrict__ out) {
  int lane = threadIdx.x & 63, wid = threadIdx.x >> 6;
  int n = blockIdx.x * 4 + wid;
  int sub = lane >> 3;
  int cg = lane & 7;
  int beg = n << 7;
  int deg = degs[n];
  int limit = beg + deg;
  int end = beg + ((deg + 15) & ~15);
  float adn = a_dst[n];
  const __half* __restrict__ hh = h2 + cg * 8;
  float4 aclo = make_float4(0.f, 0.f, 0.f, 0.f), achi = aclo;
  float s = 0.f;
  int e = beg + sub;
  bool va = e < limit, vb = e + 8 < limit;
  int t0 = csr[e], t1 = csr[e + 8];
  unsigned i0 = va ? (unsigned)t0 : 0u, i1 = vb ? (unsigned)t1 : 0u;
  float v0 = a_src[i0], v1 = a_src[i1];
  for (;;) {
    float4 galo, gahi, gblo, gbhi;
    ld_half8(hh + i0 * 64u, galo, gahi);
    ld_half8(hh + i1 * 64u, gblo, gbhi);
    float pa = va ? lrelu_exp(v0 + adn) : 0.f;
    float pb = vb ? lrelu_exp(v1 + adn) : 0.f;
    e += 16;
    bool more = e < end;
    if (more) {
      va = e < limit; vb = e + 8 < limit;
      t0 = csr[e]; t1 = csr[e + 8];
      i0 = va ? (unsigned)t0 : 0u; i1 = vb ? (unsigned)t1 : 0u;
      v0 = a_src[i0]; v1 = a_src[i1];
    }
    s += pa + pb;
    aclo.x = fmaf(pb, gblo.x, fmaf(pa, galo.x, aclo.x));
    aclo.y = fmaf(pb, gblo.y, fmaf(pa, galo.y, aclo.y));
    aclo.z = fmaf(pb, gblo.z, fmaf(pa, galo.z, aclo.z));
    aclo.w = fmaf(pb, gblo.w, fmaf(pa, galo.w, aclo.w));
    achi.x = fmaf(pb, gbhi.x, fmaf(pa, gahi.x, achi.x));
    achi.y = fmaf(pb, gbhi.y, fmaf(pa, gahi.y, achi.y));
    achi.z = fmaf(pb, gbhi.z, fmaf(pa, gahi.z, achi.z));
    achi.w = fmaf(pb, gbhi.w, fmaf(pa, gahi.w, achi.w));
    if (!more) break;
  }
#pragma unroll
  for (int m = 8; m <= 32; m <<= 1) {
    aclo.x += __shfl_xor(aclo.x, m);
    aclo.y += __shfl_xor(aclo.y, m);
    aclo.z += __shfl_xor(aclo.z, m);
    aclo.w += __shfl_xor(aclo.w, m);
    achi.x += __shfl_xor(achi.x, m);
    achi.y += __shfl_xor(achi.y, m);
    achi.z += __shfl_xor(achi.z, m);
    achi.w += __shfl_xor(achi.w, m);
    s += __shfl_xor(s, m);
  }
  if (sub == 0) {
    float inv = 1.f / (s + 1e-16f);
    const float* bp = b2 + cg * 8;
    float4 b_lo = *reinterpret_cast<const float4*>(bp);
    float4 b_hi = *reinterpret_cast<const float4*>(bp + 4);
    float4 olo, ohi;
    olo.x = fmaxf(fmaf(aclo.x, inv, b_lo.x), 0.f);
    olo.y = fmaxf(fmaf(aclo.y, inv, b_lo.y), 0.f);
    olo.z = fmaxf(fmaf(aclo.z, inv, b_lo.z), 0.f);
    olo.w = fmaxf(fmaf(aclo.w, inv, b_lo.w), 0.f);
    ohi.x = fmaxf(fmaf(achi.x, inv, b_hi.x), 0.f);
    ohi.y = fmaxf(fmaf(achi.y, inv, b_hi.y), 0.f);
    ohi.z = fmaxf(fmaf(achi.z, inv, b_hi.z), 0.f);
    ohi.w = fmaxf(fmaf(achi.w, inv, b_hi.w), 0.f);
    float* op = &out[(size_t)n * 64 + cg * 8];
    *reinterpret_cast<float4*>(op) = olo;
    *reinterpret_cast<float4*>(op + 4) = ohi;
  }
}

// ---- layer 2 GEMM: split-K, blockIdx.y = K-chunk (grid 157x5), partials out ----

__global__ __launch_bounds__(256) void k_gemm2(const float* __restrict__ out1, const float* __restrict__ W2,
                                               float* __restrict__ h2part) {
  __shared__ float xs[64][65];
  int t = threadIdx.x;
  int rb = blockIdx.x * 64;
  int kc = blockIdx.y;
#pragma unroll
  for (int i = 0; i < 4; ++i) {
    int idx = t + 256 * i;
    int kq = (idx & 15) * 4;
    int row = idx >> 4;
    int gr = rb + row;
    float4 v = make_float4(0.f, 0.f, 0.f, 0.f);
    if (gr < N_NODES) v = *reinterpret_cast<const float4*>(&out1[(size_t)gr * 320 + kc * 64 + kq]);
    xs[kq + 0][row] = v.x; xs[kq + 1][row] = v.y; xs[kq + 2][row] = v.z; xs[kq + 3][row] = v.w;
  }
  __syncthreads();
  int cg = t & 15, rg = t >> 4;
  int c0 = cg * 4, r0 = rg * 4;
  const float* __restrict__ wp = W2 + (size_t)kc * 64 * 64 + c0;
  float4 a0 = make_float4(0.f,0.f,0.f,0.f), a1 = a0, a2 = a0, a3 = a0;
#pragma unroll 4
  for (int k = 0; k < 64; ++k) {
    float4 xv = *reinterpret_cast<const float4*>(&xs[k][r0]);
    float4 wv = *reinterpret_cast<const float4*>(&wp[(size_t)k * 64]);
    a0.x = fmaf(xv.x, wv.x, a0.x); a0.y = fmaf(xv.x, wv.y, a0.y); a0.z = fmaf(xv.x, wv.z, a0.z); a0.w = fmaf(xv.x, wv.w, a0.w);
    a1.x = fmaf(xv.y, wv.x, a1.x); a1.y = fmaf(xv.y, wv.y, a1.y); a1.z = fmaf(xv.y, wv.z, a1.z); a1.w = fmaf(xv.y, wv.w, a1.w);
    a2.x = fmaf(xv.z, wv.x, a2.x); a2.y = fmaf(xv.z, wv.y, a2.y); a2.z = fmaf(xv.z, wv.z, a2.z); a2.w = fmaf(xv.z, wv.w, a2.w);
    a3.x = fmaf(xv.w, wv.x, a3.x); a3.y = fmaf(xv.w, wv.y, a3.y); a3.z = fmaf(xv.w, wv.z, a3.z); a3.w = fmaf(xv.w, wv.w, a3.w);
  }
  float* __restrict__ hp = h2part + (size_t)kc * N_NODES * 64;
#pragma unroll
  for (int rr = 0; rr < 4; ++rr) {
    float4 ar = (rr == 0) ? a0 : (rr == 1) ? a1 : (rr == 2) ? a2 : a3;
    int gr = rb + r0 + rr;
    if (gr < N_NODES) *reinterpret_cast<float4*>(&hp[(size_t)gr * 64 + c0]) = ar;
  }
}

// ---- reduce 5 partials (fixed order) + att dots; h2 stored fp16 ----

__global__ __launch_bounds__(256) void k_hred2(const float* __restrict__ h2part,
                                               const float* __restrict__ att_src, const float* __restrict__ att_dst,
                                               __half* __restrict__ h2, float* __restrict__ a_src,
                                               float* __restrict__ a_dst) {
  int n = blockIdx.x * 4 + (threadIdx.x >> 6);
  int c = threadIdx.x & 63;
  if (n >= N_NODES) return;
  float v = 0.f;
#pragma unroll
  for (int kc = 0; kc < 5; ++kc) v += h2part[((size_t)kc * N_NODES + n) * 64 + c];
  float vs = v * att_src[c], vd = v * att_dst[c];
  float vnext = __shfl_down(v, 1);
  if ((c & 1) == 0) {
    __half2 p = __float22half2_rn(make_float2(v, vnext));
    *reinterpret_cast<unsigned*>(&h2[(size_t)n * 64 + c]) = *reinterpret_cast<const unsigned*>(&p);
  }
  for (int off = 32; off; off >>= 1) {
    vs += __shfl_down(vs, off);
    vd += __shfl_down(vd, off);
  }
  if (c == 0) { a_src[n] = vs; a_dst[n] = vd; }
}

// ---------------- launch ----------------

extern "C" void kernel_launch(void* const* d_in, const int* in_sizes, int n_in,
                              void* d_out, int out_size, void* d_ws, size_t ws_size,
                              hipStream_t stream) {
  (void)in_sizes; (void)n_in; (void)out_size; (void)ws_size;
  const float* x    = (const float*)d_in[0];
  const int*   ei   = (const int*)d_in[1];
  const float* W1   = (const float*)d_in[2];
  const float* as1w = (const float*)d_in[3];
  const float* ad1w = (const float*)d_in[4];
  const float* b1   = (const float*)d_in[5];
  const float* W2   = (const float*)d_in[6];
  const float* as2w = (const float*)d_in[7];
  const float* ad2w = (const float*)d_in[8];
  const float* b2   = (const float*)d_in[9];
  float* out = (float*)d_out;

  char* ws = (char*)d_ws;
  size_t off = 0;
  auto alloc = [&](size_t bytes) -> void* {
    void* p = ws + off;
    off += (bytes + 255) & ~(size_t)255;
    return p;
  };
  __half* h1     = (__half*)alloc((size_t)N_NODES * 320 * 2);
  float*  out1   = (float*)alloc((size_t)N_NODES * 320 * 4);
  __half* h2     = (__half*)alloc((size_t)N_NODES * 64 * 2);
  float*  h2part = (float*)alloc((size_t)5 * N_NODES * 64 * 4);
  float*  a_src1 = (float*)alloc((size_t)5 * N_NODES * 4);
  float*  a_dst1 = (float*)alloc((size_t)5 * N_NODES * 4);
  float*  a_src2 = (float*)alloc((size_t)N_NODES * 4);
  float*  a_dst2 = (float*)alloc((size_t)N_NODES * 4);
  int*    cursor = (int*)alloc((size_t)N_NODES * 4);
  int*    csr    = (int*)alloc((size_t)N_NODES * CAP * 4);  // pad slots never interpreted: no init

  k_init<<<(N_NODES + 255) / 256, 256, 0, stream>>>(cursor);
  k_gemm1_scatter<<<NB_G1 + NB_SCT, 256, 0, stream>>>(x, W1, as1w, ad1w, h1, a_src1, a_dst1,
                                                      ei, cursor, csr);
  {
    dim3 g(N_NODES / 4, 5);
    k_agg1 <<<g, 256, 0, stream>>>(h1, a_src1, a_dst1, b1, cursor, csr, out1);
  }
  {
    dim3 g((N_NODES + 63) / 64, 5);
    k_gemm2<<<g, 256, 0, stream>>>(out1, W2, h2part);
  }
  k_hred2<<<(N_NODES + 3) / 4, 256, 0, stream>>>(h2part, as2w, ad2w, h2, a_src2, a_dst2);
  k_agg2 <<<N_NODES / 4, 256, 0, stream>>>(h2, a_src2, a_dst2, b2, cursor, csr, out);
}